// Round 2
// baseline (244.381 us; speedup 1.0000x reference)
//
#include <hip/hip_runtime.h>
#include <math.h>

// Problem constants (from reference): N=65536 rows, D=512 features, K=5 centroids.
#define LFR_N 65536
#define LFR_D 512
#define LFR_K 5
#define ROWS  4   // rows per wave; grid sized so each wave does exactly one block of ROWS rows

// Native vector type for nontemporal builtins (HIP float4 is a class -> rejected).
typedef float fx4 __attribute__((ext_vector_type(4)));

// R2 changes vs the 81us kernel (theory: serialization-bound, pipes adding not overlapping):
//  (a) dist'_k = sum_d (-2*alpha*c_k)*x + sum_d alpha*c_k^2   (drop row-constant
//      sum alpha*x^2 -- softmax is shift-invariant). 48 VALU ops/row vs 120.
//  (b) reduce-scatter(xor32,xor16) -> 4-step butterfly on 5 values -> allgather:
//      50 ds_swizzles/wave vs 120, softmax computed once per lane instead of x4.
//      NOTE: all value selects are ?: on VALUES with compile-time array indices
//      (runtime indices demote private arrays to scratch -- R1 post-mortem).
//  (c) nontemporal stores for out_rec (136MB write-once) to reduce L3 eviction of x.
__global__ __launch_bounds__(256) void lfr_kernel(
    const float* __restrict__ x,        // (N, D)
    const float* __restrict__ alpha,    // (D,)
    const float* __restrict__ w,        // (K, 1)
    const float* __restrict__ cent,     // (K, D)
    float* __restrict__ out_map,        // (N, K)
    float* __restrict__ out_rec,        // (N, D)
    float* __restrict__ out_pred)       // (N,)
{
    const int lane          = threadIdx.x & 63;
    const int wave_in_block = threadIdx.x >> 6;
    const int wave_id       = blockIdx.x * (blockDim.x >> 6) + wave_in_block;
    const int rb            = wave_id * ROWS;   // first of this wave's ROWS rows
    if (rb >= LFR_N) return;

    const int d0  = lane * 8;        // this lane's 8 feature indices
    const int hi  = (lane >> 5) & 1; // row bit1 for scatter/gather
    const int mid = (lane >> 4) & 1; // row bit0

    // ---- issue all ROWS x-row loads first (independent, in flight together) ----
    float4 xl[ROWS][2];
    #pragma unroll
    for (int r = 0; r < ROWS; ++r) {
        const float* xr = x + (size_t)(rb + r) * LFR_D + d0;
        xl[r][0] = *(const float4*)(xr);
        xl[r][1] = *(const float4*)(xr + 4);
    }

    // ---- per-lane constants (L1/L2-hit after first waves) ----
    float al[8];
    {
        float4 a0 = *(const float4*)(alpha + d0);
        float4 a1 = *(const float4*)(alpha + d0 + 4);
        al[0]=a0.x; al[1]=a0.y; al[2]=a0.z; al[3]=a0.w;
        al[4]=a1.x; al[5]=a1.y; al[6]=a1.z; al[7]=a1.w;
    }
    float c[LFR_K][8];
    #pragma unroll
    for (int k = 0; k < LFR_K; ++k) {
        float4 c0 = *(const float4*)(cent + k * LFR_D + d0);
        float4 c1 = *(const float4*)(cent + k * LFR_D + d0 + 4);
        c[k][0]=c0.x; c[k][1]=c0.y; c[k][2]=c0.z; c[k][3]=c0.w;
        c[k][4]=c1.x; c[k][5]=c1.y; c[k][6]=c1.z; c[k][7]=c1.w;
    }
    // m2a = -2*alpha ; cst_k = lane-partial of sum_d alpha*c_k^2
    float m2a[8];
    #pragma unroll
    for (int j = 0; j < 8; ++j) m2a[j] = -2.0f * al[j];
    float cst[LFR_K];
    #pragma unroll
    for (int k = 0; k < LFR_K; ++k) {
        float s = 0.0f;
        #pragma unroll
        for (int j = 0; j < 8; ++j) {
            float u = al[j] * c[k][j];
            s = fmaf(u, c[k][j], s);
        }
        cst[k] = s;
    }

    // ---- partial shifted distances: p[r][k] = cst_k + sum_j c_kj * (-2*alpha_j*x_j) ----
    float xv[ROWS][8];
    #pragma unroll
    for (int r = 0; r < ROWS; ++r) {
        xv[r][0]=xl[r][0].x; xv[r][1]=xl[r][0].y; xv[r][2]=xl[r][0].z; xv[r][3]=xl[r][0].w;
        xv[r][4]=xl[r][1].x; xv[r][5]=xl[r][1].y; xv[r][6]=xl[r][1].z; xv[r][7]=xl[r][1].w;
    }
    float p[ROWS][LFR_K];
    #pragma unroll
    for (int r = 0; r < ROWS; ++r) {
        float v[8];
        #pragma unroll
        for (int j = 0; j < 8; ++j) v[j] = m2a[j] * xv[r][j];
        #pragma unroll
        for (int k = 0; k < LFR_K; ++k) {
            float acc = cst[k];
            #pragma unroll
            for (int j = 0; j < 8; ++j) acc = fmaf(c[k][j], v[j], acc);
            p[r][k] = acc;
        }
    }

    // ---- reduce-scatter: rows -> 16-lane groups (group g = lane>>4 owns row rb+g) ----
    // step 1 (xor 32): keep rows whose bit1 == hi         (10 swz + 10 add + 20 sel)
    float q[2][LFR_K];
    #pragma unroll
    for (int r2 = 0; r2 < 2; ++r2) {
        #pragma unroll
        for (int k = 0; k < LFR_K; ++k) {
            float send = hi ? p[r2][k]     : p[2 + r2][k];
            float keep = hi ? p[2 + r2][k] : p[r2][k];
            q[r2][k] = keep + __shfl_xor(send, 32);
        }
    }
    // step 2 (xor 16): keep row whose bit0 == mid          (5 swz + 5 add + 10 sel)
    float s[LFR_K];
    #pragma unroll
    for (int k = 0; k < LFR_K; ++k) {
        float send = mid ? q[0][k] : q[1][k];
        float keep = mid ? q[1][k] : q[0][k];
        s[k] = keep + __shfl_xor(send, 16);
    }
    // butterfly within the 16-lane group                  (20 swz + 20 add)
    #pragma unroll
    for (int off = 8; off > 0; off >>= 1) {
        #pragma unroll
        for (int k = 0; k < LFR_K; ++k)
            s[k] += __shfl_xor(s[k], off);
    }

    // ---- softmax over K, once per lane (row g = lane>>4) ----
    float e[LFR_K];
    {
        float mx = s[0];
        #pragma unroll
        for (int k = 1; k < LFR_K; ++k) mx = fmaxf(mx, s[k]);
        float sum = 0.0f;
        #pragma unroll
        for (int k = 0; k < LFR_K; ++k) { e[k] = __expf(s[k] - mx); sum += e[k]; }
        float inv = 1.0f / sum;
        #pragma unroll
        for (int k = 0; k < LFR_K; ++k) e[k] *= inv;
    }

    // ---- mapping + pred: sublane 0 of each 16-lane group writes its row ----
    if ((lane & 15) == 0) {
        const int g = lane >> 4;
        float sigw[LFR_K];
        #pragma unroll
        for (int k = 0; k < LFR_K; ++k)
            sigw[k] = 1.0f / (1.0f + __expf(-w[k]));
        float* mp = out_map + (size_t)(rb + g) * LFR_K;
        *(float4*)(mp) = make_float4(e[0], e[1], e[2], e[3]);
        mp[4] = e[4];
        float pr = e[0] * sigw[0];
        #pragma unroll
        for (int k = 1; k < LFR_K; ++k) pr = fmaf(e[k], sigw[k], pr);
        out_pred[rb + g] = pr;
    }

    // ---- allgather m back to all lanes (15 swz + 30 sel), compile-time row index ----
    float mA[2][LFR_K];            // rows {2*hi+0, 2*hi+1}
    #pragma unroll
    for (int k = 0; k < LFR_K; ++k) {
        float o = __shfl_xor(e[k], 16);
        mA[0][k] = mid ? o    : e[k];
        mA[1][k] = mid ? e[k] : o;
    }
    float M[ROWS][LFR_K];
    #pragma unroll
    for (int r2 = 0; r2 < 2; ++r2) {
        #pragma unroll
        for (int k = 0; k < LFR_K; ++k) {
            float o = __shfl_xor(mA[r2][k], 32);
            M[r2][k]     = hi ? o         : mA[r2][k];
            M[2 + r2][k] = hi ? mA[r2][k] : o;
        }
    }

    // ---- reconstruction: rec[d] = sum_k M[k] * c[k][d] (nontemporal: write-once) ----
    #pragma unroll
    for (int r = 0; r < ROWS; ++r) {
        float rv[8];
        #pragma unroll
        for (int j = 0; j < 8; ++j) {
            float acc = M[r][0] * c[0][j];
            #pragma unroll
            for (int k = 1; k < LFR_K; ++k) acc = fmaf(M[r][k], c[k][j], acc);
            rv[j] = acc;
        }
        float* rr = out_rec + (size_t)(rb + r) * LFR_D + d0;
        fx4 v0 = { rv[0], rv[1], rv[2], rv[3] };
        fx4 v1 = { rv[4], rv[5], rv[6], rv[7] };
        __builtin_nontemporal_store(v0, (fx4*)(rr));
        __builtin_nontemporal_store(v1, (fx4*)(rr + 4));
    }
}

extern "C" void kernel_launch(void* const* d_in, const int* in_sizes, int n_in,
                              void* d_out, int out_size, void* d_ws, size_t ws_size,
                              hipStream_t stream) {
    const float* x     = (const float*)d_in[0];   // (N, D)
    // d_in[1] = is_protected — unused by the reference computation
    const float* alpha = (const float*)d_in[2];   // (D,)
    const float* w     = (const float*)d_in[3];   // (K, 1)
    const float* cent  = (const float*)d_in[4];   // (K, D)

    float* out   = (float*)d_out;
    float* o_map = out;                                         // N*K
    float* o_rec = out + (size_t)LFR_N * LFR_K;                 // N*D
    float* o_prd = out + (size_t)LFR_N * LFR_K + (size_t)LFR_N * LFR_D;  // N

    // 4096 blocks x 256 threads = 16384 waves x ROWS=4 rows = 65536 rows,
    // exactly one row-block per wave (max TLP, no grid-stride loop).
    dim3 grid(LFR_N / (4 * ROWS)), block(256);
    lfr_kernel<<<grid, block, 0, stream>>>(x, alpha, w, cent, o_map, o_rec, o_prd);
}